// Round 2
// baseline (990.134 us; speedup 1.0000x reference)
//
#include <hip/hip_runtime.h>

// Problem constants (fixed by setup_inputs): E=800000, N=50000, G=16, EMB=64.
#define EMB 64

// ---------------------------------------------------------------------------
// Kernel 0 (prep): W1 transpose -> W1T[o*64+i]; per-node edge counts;
// per-graph node counts. Grid covers E threads (E > N > 4096).
// ---------------------------------------------------------------------------
__global__ __launch_bounds__(256) void prep_kernel(
    const float* __restrict__ W1, float* __restrict__ W1T,
    const int* __restrict__ eidx, int* __restrict__ ecnt, int E,
    const int* __restrict__ batch, int* __restrict__ gN, int N)
{
    int t = blockIdx.x * blockDim.x + threadIdx.x;
    if (t < 4096) { int o = t >> 6, i = t & 63; W1T[t] = W1[i * 64 + o]; }
    if (t < N) atomicAdd(&gN[batch[t]], 1);
    if (t < E) atomicAdd(&ecnt[eidx[t]], 1);
}

// ---------------------------------------------------------------------------
// Kernel 1: per-edge fused
//   y = x@W1 ; acc_c = b2 + sum_o W2[o]*silu(a_c*y_o + b1[o])
// for the 6 unique symmetric components a_c of d (x) d, then accumulate
// acc_c / ecnt[n] into per-graph LDS bins -> 96 global atomics per block.
// launch_bounds(256,4): 128-VGPR budget so the 64-float x row stays
// register-resident across the o-loop (at default budget the compiler
// re-loaded x from memory every iteration -> 72% stall, round 1).
// ---------------------------------------------------------------------------
__global__ __launch_bounds__(256, 4) void edge_kernel(
    const float* __restrict__ dvec, const float* __restrict__ x_edge,
    const int*   __restrict__ eidx, const int* __restrict__ batch,
    const int*   __restrict__ ecnt,
    const float* __restrict__ W1T, const float* __restrict__ b1,
    const float* __restrict__ W2,  const float* __restrict__ b2,
    float* __restrict__ gsum, int E)
{
    __shared__ float sh[96];
    int tid = threadIdx.x;
    if (tid < 96) sh[tid] = 0.f;
    __syncthreads();

    int e = blockIdx.x * 256 + tid;
    float acc[6];
    float scale = 0.f;
    int g = 0;

    if (e < E) {
        float d0 = dvec[3 * e + 0];
        float d1 = dvec[3 * e + 1];
        float d2 = dvec[3 * e + 2];
        float a[6] = { d0 * d0, d1 * d1, d2 * d2, d0 * d1, d0 * d2, d1 * d2 };

        // x row (64 floats) -> registers, float4-vectorized.
        float4 xv[EMB / 4];
        const float4* xr = (const float4*)(x_edge + (size_t)e * EMB);
        #pragma unroll
        for (int k = 0; k < EMB / 4; ++k) xv[k] = xr[k];

        float bb2 = b2[0];
        #pragma unroll
        for (int c = 0; c < 6; ++c) acc[c] = bb2;

        const float NL2E = -1.442695040888963f;  // -log2(e)

        for (int o = 0; o < EMB; ++o) {
            // y_o = x . W1[:,o]; W1T row o is wave-uniform -> scalar loads.
            const float* w = W1T + o * EMB;
            float y0 = 0.f, y1 = 0.f, y2 = 0.f, y3 = 0.f;
            #pragma unroll
            for (int k = 0; k < EMB / 4; ++k) {
                y0 = fmaf(xv[k].x, w[4 * k + 0], y0);
                y1 = fmaf(xv[k].y, w[4 * k + 1], y1);
                y2 = fmaf(xv[k].z, w[4 * k + 2], y2);
                y3 = fmaf(xv[k].w, w[4 * k + 3], y3);
            }
            float y  = (y0 + y1) + (y2 + y3);
            float b  = b1[o];
            float w2 = W2[o];
            float yl = y * NL2E;
            float bl = b * NL2E;
            #pragma unroll
            for (int c = 0; c < 6; ++c) {
                float t  = fmaf(a[c], yl, bl);                  // -z*log2(e)
                float ex = __builtin_amdgcn_exp2f(t);           // e^{-z}
                float r  = __builtin_amdgcn_rcpf(1.0f + ex);    // sigmoid(z)
                float z  = fmaf(a[c], y, b);
                acc[c]   = fmaf(w2, z * r, acc[c]);             // += W2[o]*silu(z)
            }
        }

        int n = eidx[e];
        g = batch[n];
        scale = 1.0f / (float)max(ecnt[n], 1);
    }

    if (e < E) {
        #pragma unroll
        for (int c = 0; c < 6; ++c)
            atomicAdd(&sh[g * 6 + c], acc[c] * scale);
    }
    __syncthreads();
    if (tid < 96) atomicAdd(gsum + tid, sh[tid]);
}

// ---------------------------------------------------------------------------
// Kernel 2: finalize — divide by per-graph node count, expand 6 -> 9.
// ---------------------------------------------------------------------------
__global__ void final_kernel(const float* __restrict__ gsum,
                             const int* __restrict__ gN,
                             float* __restrict__ out)
{
    int g = threadIdx.x;
    if (g >= 16) return;
    float inv = 1.0f / fmaxf((float)gN[g], 1.0f);
    float m0 = gsum[g * 6 + 0] * inv;  // d0d0
    float m1 = gsum[g * 6 + 1] * inv;  // d1d1
    float m2 = gsum[g * 6 + 2] * inv;  // d2d2
    float m3 = gsum[g * 6 + 3] * inv;  // d0d1
    float m4 = gsum[g * 6 + 4] * inv;  // d0d2
    float m5 = gsum[g * 6 + 5] * inv;  // d1d2
    float* p = out + g * 9;
    p[0] = m0; p[1] = m3; p[2] = m4;
    p[3] = m3; p[4] = m1; p[5] = m5;
    p[6] = m4; p[7] = m5; p[8] = m2;
}

// ---------------------------------------------------------------------------
extern "C" void kernel_launch(void* const* d_in, const int* in_sizes, int n_in,
                              void* d_out, int out_size, void* d_ws, size_t ws_size,
                              hipStream_t stream) {
    const float* dvec   = (const float*)d_in[0];   // [E,3]
    const float* x_edge = (const float*)d_in[1];   // [E,64]
    const int*   eidx   = (const int*)d_in[2];     // [E]
    const int*   batch  = (const int*)d_in[3];     // [N] sorted
    const float* W1     = (const float*)d_in[6];   // [64,64] (in,out)
    const float* b1     = (const float*)d_in[7];   // [64]
    const float* W2     = (const float*)d_in[8];   // [64,1]
    const float* b2     = (const float*)d_in[9];   // [1]

    int E = in_sizes[0] / 3;   // 800000
    int N = in_sizes[3];       // 50000

    // ws layout: ecnt[N] int | gN[16] int | gsum[96] float | W1T[4096] float
    int*   ecnt = (int*)d_ws;
    int*   gN   = ecnt + N;
    float* gsum = (float*)(gN + 16);
    float* W1T  = gsum + 96;

    hipMemsetAsync(d_ws, 0, (size_t)(N + 16 + 96) * 4, stream);

    int blocks = (E + 255) / 256;
    prep_kernel<<<blocks, 256, 0, stream>>>(W1, W1T, eidx, ecnt, E, batch, gN, N);
    edge_kernel<<<blocks, 256, 0, stream>>>(dvec, x_edge, eidx, batch, ecnt,
                                            W1T, b1, W2, b2, gsum, E);
    final_kernel<<<1, 64, 0, stream>>>(gsum, gN, (float*)d_out);
}

// Round 3
// 705.638 us; speedup vs baseline: 1.4032x; 1.4032x over previous
//
#include <hip/hip_runtime.h>

// Problem constants (fixed by setup_inputs): E=800000, N=50000, G=16, EMB=64.
#define EMB  64
#define NREP 128   // replicas for per-graph accumulation (spread atomic lines)

// ---------------------------------------------------------------------------
// Kernel 0: W1 [in,out] -> W1T[o*64+i] (row per output => uniform s_loads).
// ---------------------------------------------------------------------------
__global__ void w1t_kernel(const float* __restrict__ W1, float* __restrict__ W1T) {
    int t = blockIdx.x * blockDim.x + threadIdx.x;   // 4096 threads
    int o = t >> 6, i = t & 63;
    W1T[t] = W1[i * 64 + o];
}

// ---------------------------------------------------------------------------
// Kernel 1: per-edge fused  y = x@W1 ; acc_c = b2 + sum_o W2[o]*silu(a_c*y_o+b1[o])
// for the 6 unique components of the symmetric outer product d(x)d.
// o-loop chunked 4x16 so live state ~55 VGPR (round-1/2 spilled x[64] to
// scratch -> 13TB L2 traffic -> 390us; chunking makes spill impossible).
// Scatters UNNORMALIZED acc[6] + count into node_acc[n][8] (7 same-line
// atomics/thread -- measured-OK pattern at 14.4 atomics/ns in round 1).
// ---------------------------------------------------------------------------
__global__ __launch_bounds__(256) void edge_kernel(
    const float* __restrict__ dvec, const float* __restrict__ x_edge,
    const int*   __restrict__ eidx,
    const float* __restrict__ W1T, const float* __restrict__ b1,
    const float* __restrict__ W2,  const float* __restrict__ b2,
    float* __restrict__ node_acc, int E)
{
    int e = blockIdx.x * 256 + threadIdx.x;
    if (e >= E) return;

    float d0 = dvec[3 * e + 0];
    float d1 = dvec[3 * e + 1];
    float d2 = dvec[3 * e + 2];
    float a[6] = { d0 * d0, d1 * d1, d2 * d2, d0 * d1, d0 * d2, d1 * d2 };

    float bb2 = b2[0];
    float acc[6];
    #pragma unroll
    for (int c = 0; c < 6; ++c) acc[c] = bb2;

    const float4* xr = (const float4*)(x_edge + (size_t)e * EMB);
    const float NL2E = -1.442695040888963f;  // -log2(e)

    #pragma unroll 1
    for (int c4 = 0; c4 < 4; ++c4) {
        // Block LICM from hoisting all 64 x floats out of the chunk loop
        // (that hoist is exactly the round-1 spill).
        asm volatile("" ::: "memory");

        float y[16];
        #pragma unroll
        for (int j = 0; j < 16; ++j) y[j] = 0.f;

        const float* wbase = W1T + c4 * 16 * 64;   // rows o = c4*16 .. c4*16+15

        #pragma unroll 4
        for (int k = 0; k < 16; ++k) {
            float4 xk = xr[k];                      // re-read per chunk (L2-hot)
            #pragma unroll
            for (int j = 0; j < 16; ++j) {
                const float* w = wbase + j * 64 + 4 * k;   // uniform -> s_load
                y[j] = fmaf(xk.x, w[0], y[j]);
                y[j] = fmaf(xk.y, w[1], y[j]);
                y[j] = fmaf(xk.z, w[2], y[j]);
                y[j] = fmaf(xk.w, w[3], y[j]);
            }
        }

        #pragma unroll
        for (int j = 0; j < 16; ++j) {
            int o = c4 * 16 + j;
            float yv = y[j];
            float b  = b1[o];
            float w2 = W2[o];
            float yl = yv * NL2E;
            float bl = b  * NL2E;
            #pragma unroll
            for (int c = 0; c < 6; ++c) {
                float t  = fmaf(a[c], yl, bl);                // -z*log2(e)
                float ex = __builtin_amdgcn_exp2f(t);         // e^{-z}
                float r  = __builtin_amdgcn_rcpf(1.0f + ex);  // sigmoid(z)
                float z  = fmaf(a[c], yv, b);
                acc[c]   = fmaf(w2, z * r, acc[c]);           // += W2[o]*silu(z)
            }
        }
    }

    int n = eidx[e];
    float* p = node_acc + (size_t)n * 8;   // comps 0..5, count at [6]
    #pragma unroll
    for (int c = 0; c < 6; ++c) atomicAdd(p + c, acc[c]);
    atomicAdd(p + 6, 1.0f);
}

// ---------------------------------------------------------------------------
// Kernel 2: node means -> replica-spread per-graph sums; also record sorted
// batch segment boundaries (zero atomics -- round-2's gN histogram was a
// 50k-atomics-to-one-cacheline storm).
// ---------------------------------------------------------------------------
__global__ __launch_bounds__(256) void node_kernel(
    const float* __restrict__ node_acc, const int* __restrict__ batch,
    float* __restrict__ repsum, int* __restrict__ gStart, int N)
{
    int n = blockIdx.x * blockDim.x + threadIdx.x;
    if (n >= N) return;
    int g = batch[n];
    if (n == 0 || batch[n - 1] != g) gStart[g] = n;   // sorted: unique writer

    const float* p = node_acc + (size_t)n * 8;
    float cnt = p[6];
    float inv = 1.0f / fmaxf(cnt, 1.0f);              // mean; 0-edge node -> 0
    int rep = blockIdx.x & (NREP - 1);
    float* line = repsum + ((size_t)rep * 16 + g) * 16;   // 64B line per (rep,g)
    #pragma unroll
    for (int c = 0; c < 6; ++c) atomicAdd(line + c, p[c] * inv);
}

// ---------------------------------------------------------------------------
// Kernel 3: finalize — sum replicas, derive per-graph node counts from the
// boundary array, divide, expand 6 symmetric comps -> 9. One block.
// ---------------------------------------------------------------------------
__global__ void final_kernel(const float* __restrict__ repsum,
                             const int* __restrict__ gStart,
                             float* __restrict__ out, int N)
{
    __shared__ float sh[96];
    __shared__ int gs[17];
    int t = threadIdx.x;   // 128 threads
    if (t < 96) {
        int g = t / 6, c = t % 6;
        float s = 0.f;
        for (int r = 0; r < NREP; ++r) s += repsum[(size_t)r * 256 + g * 16 + c];
        sh[g * 6 + c] = s;
    }
    if (t == 0) {
        gs[16] = N;
        for (int g = 15; g >= 0; --g) {
            unsigned v = (unsigned)gStart[g];
            gs[g] = (v > (unsigned)gs[g + 1]) ? gs[g + 1] : (int)v;  // empty-graph fix
        }
    }
    __syncthreads();
    if (t < 16) {
        int gN = gs[t + 1] - gs[t];
        float inv = 1.0f / fmaxf((float)gN, 1.0f);
        float m0 = sh[t * 6 + 0] * inv;  // d0d0
        float m1 = sh[t * 6 + 1] * inv;  // d1d1
        float m2 = sh[t * 6 + 2] * inv;  // d2d2
        float m3 = sh[t * 6 + 3] * inv;  // d0d1
        float m4 = sh[t * 6 + 4] * inv;  // d0d2
        float m5 = sh[t * 6 + 5] * inv;  // d1d2
        float* p = out + t * 9;
        p[0] = m0; p[1] = m3; p[2] = m4;
        p[3] = m3; p[4] = m1; p[5] = m5;
        p[6] = m4; p[7] = m5; p[8] = m2;
    }
}

// ---------------------------------------------------------------------------
extern "C" void kernel_launch(void* const* d_in, const int* in_sizes, int n_in,
                              void* d_out, int out_size, void* d_ws, size_t ws_size,
                              hipStream_t stream) {
    const float* dvec   = (const float*)d_in[0];   // [E,3]
    const float* x_edge = (const float*)d_in[1];   // [E,64]
    const int*   eidx   = (const int*)d_in[2];     // [E]
    const int*   batch  = (const int*)d_in[3];     // [N] sorted
    const float* W1     = (const float*)d_in[6];   // [64,64] (in,out)
    const float* b1     = (const float*)d_in[7];   // [64]
    const float* W2     = (const float*)d_in[8];   // [64,1]
    const float* b2     = (const float*)d_in[9];   // [1]

    int E = in_sizes[0] / 3;   // 800000
    int N = in_sizes[3];       // 50000

    // ws layout: node_acc[N*8] f | repsum[NREP*16*16] f | W1T[4096] f | gStart[17] i
    float* node_acc = (float*)d_ws;
    float* repsum   = node_acc + (size_t)N * 8;
    float* W1T      = repsum + NREP * 256;
    int*   gStart   = (int*)(W1T + 4096);

    hipMemsetAsync(node_acc, 0, ((size_t)N * 8 + NREP * 256) * 4, stream);
    hipMemsetAsync(gStart, 0xFF, 17 * 4, stream);

    w1t_kernel<<<16, 256, 0, stream>>>(W1, W1T);
    edge_kernel<<<(E + 255) / 256, 256, 0, stream>>>(dvec, x_edge, eidx,
                                                     W1T, b1, W2, b2, node_acc, E);
    node_kernel<<<(N + 255) / 256, 256, 0, stream>>>(node_acc, batch, repsum, gStart, N);
    final_kernel<<<1, 128, 0, stream>>>(repsum, gStart, (float*)d_out, N);
}

// Round 4
// 559.243 us; speedup vs baseline: 1.7705x; 1.2618x over previous
//
#include <hip/hip_runtime.h>

// Problem constants: E=800000 (=3125*256), N=50000, G=16, EMB=64.
#define EMB  64
#define NREP 64   // replicas for per-graph atomic spreading

typedef __attribute__((ext_vector_type(8))) short bf16x8;
typedef __attribute__((ext_vector_type(4))) float f32x4;

union BF8 { bf16x8 v; short s[8]; };

// float -> bf16 bits, round-to-nearest-even (finite inputs).
static __device__ __forceinline__ short f2bf(float f) {
    unsigned u = __float_as_uint(f);
    u += 0x7fffu + ((u >> 16) & 1u);
    return (short)(u >> 16);
}

// ---------------------------------------------------------------------------
// Edge kernel. Per block: 256 edges, 4 waves, wave w owns edges [w*64, w*64+64).
// Phase 1 (per wave): Y = X@W1 via mfma_f32_16x16x32_bf16.
//   A-frags (x rows) loaded straight from global in A-layout (x read ONCE —
//   round-3's 4-pass chunking refetched x 4x from HBM = 830 MB).
//   B-frags (W1) built once, kept in 32 VGPRs.
//   D (C-layout: col=lane&15 -> o, row=quad*4+reg -> edge) -> LDS [o][edge],
//   edge index XOR-swizzled by 4*(o&15) so the b128 writes are conflict-free.
// Phase 2: thread t owns edge t; reads y[64] from LDS (conflict-free),
//   does the 6-component silu sum, scatters unnormalized acc+count to
//   node_acc[n][8] (the round-1-proven atomic pattern).
// ---------------------------------------------------------------------------
__global__ __launch_bounds__(256, 2) void edge_kernel(
    const float* __restrict__ dvec, const float* __restrict__ x_edge,
    const int*   __restrict__ eidx,
    const float* __restrict__ W1, const float* __restrict__ b1,
    const float* __restrict__ W2, const float* __restrict__ b2,
    float* __restrict__ node_acc, int E)
{
    __shared__ float Y[4][64 * 64];   // 64 KB: per-wave [o][edge(swizzled)]
    const int tid  = threadIdx.x;
    const int wave = tid >> 6, lane = tid & 63;
    const int col  = lane & 15, quad = lane >> 4;

    // ---- B fragments: B[k = quad*8+j][n = ntile*16+col] = W1[k][o] (bf16 RNE)
    BF8 Bf[4][2];
    #pragma unroll
    for (int n = 0; n < 4; ++n) {
        #pragma unroll
        for (int kt = 0; kt < 2; ++kt) {
            const float* wp = W1 + (kt * 32 + quad * 8) * 64 + n * 16 + col;
            #pragma unroll
            for (int j = 0; j < 8; ++j) Bf[n][kt].s[j] = f2bf(wp[j * 64]);
        }
    }

    // ---- Phase 1: MFMA, 4 M-tiles of 16 edges each
    const long ebase = (long)blockIdx.x * 256 + wave * 64;
    float* Yw = &Y[wave][0];
    #pragma unroll
    for (int m = 0; m < 4; ++m) {
        long er = ebase + m * 16 + col;          // A row = lane&15
        if (er >= E) er = E - 1;                 // clamp (E%256==0 -> no-op)
        const float* xp = x_edge + (size_t)er * EMB + quad * 8;
        f32x4 xa = *(const f32x4*)(xp);
        f32x4 xb = *(const f32x4*)(xp + 4);
        f32x4 xc = *(const f32x4*)(xp + 32);
        f32x4 xd = *(const f32x4*)(xp + 36);
        BF8 A0, A1;
        A0.s[0] = f2bf(xa.x); A0.s[1] = f2bf(xa.y); A0.s[2] = f2bf(xa.z); A0.s[3] = f2bf(xa.w);
        A0.s[4] = f2bf(xb.x); A0.s[5] = f2bf(xb.y); A0.s[6] = f2bf(xb.z); A0.s[7] = f2bf(xb.w);
        A1.s[0] = f2bf(xc.x); A1.s[1] = f2bf(xc.y); A1.s[2] = f2bf(xc.z); A1.s[3] = f2bf(xc.w);
        A1.s[4] = f2bf(xd.x); A1.s[5] = f2bf(xd.y); A1.s[6] = f2bf(xd.z); A1.s[7] = f2bf(xd.w);
        #pragma unroll
        for (int n = 0; n < 4; ++n) {
            f32x4 D = { 0.f, 0.f, 0.f, 0.f };
            D = __builtin_amdgcn_mfma_f32_16x16x32_bf16(A0.v, Bf[n][0].v, D, 0, 0, 0);
            D = __builtin_amdgcn_mfma_f32_16x16x32_bf16(A1.v, Bf[n][1].v, D, 0, 0, 0);
            int o  = n * 16 + col;                       // D col -> output index
            int r0 = (m * 16 + quad * 4) ^ ((o & 15) << 2);  // swizzled edge base
            *(f32x4*)&Yw[(o << 6) + r0] = D;             // ds_write_b128
        }
    }
    __syncthreads();

    // ---- Phase 2: silu sum, thread t <-> edge (block*256 + t)
    const long e = (long)blockIdx.x * 256 + tid;
    if (e < E) {
        float d0 = dvec[3 * e + 0];
        float d1 = dvec[3 * e + 1];
        float d2 = dvec[3 * e + 2];
        float A[6] = { d0 * d0, d1 * d1, d2 * d2, d0 * d1, d0 * d2, d1 * d2 };

        float bb2 = b2[0];
        float acc[6];
        #pragma unroll
        for (int c = 0; c < 6; ++c) acc[c] = bb2;

        const float NL2E = -1.442695040888963f;  // -log2(e)
        #pragma unroll 4
        for (int o = 0; o < EMB; ++o) {
            float y  = Yw[(o << 6) + (lane ^ ((o & 15) << 2))];
            float b  = b1[o];                    // uniform -> s_load
            float w2 = W2[o];
            #pragma unroll
            for (int c = 0; c < 6; ++c) {
                float z  = fmaf(A[c], y, b);
                float ex = __builtin_amdgcn_exp2f(z * NL2E);
                float r  = __builtin_amdgcn_rcpf(1.0f + ex);
                acc[c]   = fmaf(w2, z * r, acc[c]);
            }
        }

        int n = eidx[e];
        float* p = node_acc + (size_t)n * 8;
        #pragma unroll
        for (int c = 0; c < 6; ++c) atomicAdd(p + c, acc[c]);
        atomicAdd(p + 6, 1.0f);
    }
}

// ---------------------------------------------------------------------------
// Node kernel: node means -> LDS per-graph pre-reduction (kills same-line
// storms) -> replica-spread global bins. Also records sorted-batch segment
// starts (zero atomics).
// ---------------------------------------------------------------------------
__global__ __launch_bounds__(256) void node_kernel(
    const float* __restrict__ node_acc, const int* __restrict__ batch,
    float* __restrict__ repsum, int* __restrict__ gStart, int N)
{
    __shared__ float ls[16 * 8];
    int t = threadIdx.x;
    if (t < 128) ls[t] = 0.f;
    __syncthreads();

    int n = blockIdx.x * 256 + t;
    if (n < N) {
        int g = batch[n];
        if (n == 0 || batch[n - 1] != g) gStart[g] = n;
        const float* p = node_acc + (size_t)n * 8;
        float inv = 1.0f / fmaxf(p[6], 1.0f);    // mean; 0-edge node -> 0
        #pragma unroll
        for (int c = 0; c < 6; ++c) atomicAdd(&ls[g * 8 + c], p[c] * inv);
    }
    __syncthreads();

    if (t < 128 && (t & 7) < 6) {
        float v = ls[t];
        if (v != 0.f) {
            int rep = blockIdx.x & (NREP - 1);
            atomicAdd(repsum + (size_t)rep * 128 + t, v);
        }
    }
}

// ---------------------------------------------------------------------------
// Final: sum replicas, node counts from boundaries, mean, expand 6 -> 9.
// ---------------------------------------------------------------------------
__global__ void final_kernel(const float* __restrict__ repsum,
                             const int* __restrict__ gStart,
                             float* __restrict__ out, int N)
{
    __shared__ float sh[96];
    __shared__ int gs[17];
    int t = threadIdx.x;   // 128 threads
    if (t < 96) {
        int g = t / 6, c = t % 6;
        float s = 0.f;
        for (int r = 0; r < NREP; ++r) s += repsum[(size_t)r * 128 + g * 8 + c];
        sh[t] = s;
    }
    if (t == 0) {
        gs[16] = N;
        for (int g = 15; g >= 0; --g) {
            unsigned v = (unsigned)gStart[g];
            gs[g] = (v > (unsigned)gs[g + 1]) ? gs[g + 1] : (int)v;  // empty graphs
        }
    }
    __syncthreads();
    if (t < 16) {
        int gN = gs[t + 1] - gs[t];
        float inv = 1.0f / fmaxf((float)gN, 1.0f);
        float m0 = sh[t * 6 + 0] * inv;
        float m1 = sh[t * 6 + 1] * inv;
        float m2 = sh[t * 6 + 2] * inv;
        float m3 = sh[t * 6 + 3] * inv;
        float m4 = sh[t * 6 + 4] * inv;
        float m5 = sh[t * 6 + 5] * inv;
        float* p = out + t * 9;
        p[0] = m0; p[1] = m3; p[2] = m4;
        p[3] = m3; p[4] = m1; p[5] = m5;
        p[6] = m4; p[7] = m5; p[8] = m2;
    }
}

// ---------------------------------------------------------------------------
extern "C" void kernel_launch(void* const* d_in, const int* in_sizes, int n_in,
                              void* d_out, int out_size, void* d_ws, size_t ws_size,
                              hipStream_t stream) {
    const float* dvec   = (const float*)d_in[0];   // [E,3]
    const float* x_edge = (const float*)d_in[1];   // [E,64]
    const int*   eidx   = (const int*)d_in[2];     // [E]
    const int*   batch  = (const int*)d_in[3];     // [N] sorted
    const float* W1     = (const float*)d_in[6];   // [64,64] (in,out)
    const float* b1     = (const float*)d_in[7];   // [64]
    const float* W2     = (const float*)d_in[8];   // [64,1]
    const float* b2     = (const float*)d_in[9];   // [1]

    int E = in_sizes[0] / 3;   // 800000
    int N = in_sizes[3];       // 50000

    // ws: node_acc[N*8] f | repsum[NREP*128] f | gStart[17] i
    float* node_acc = (float*)d_ws;
    float* repsum   = node_acc + (size_t)N * 8;
    int*   gStart   = (int*)(repsum + (size_t)NREP * 128);

    hipMemsetAsync(node_acc, 0, ((size_t)N * 8 + NREP * 128) * 4, stream);
    hipMemsetAsync(gStart, 0xFF, 17 * 4, stream);

    edge_kernel<<<(E + 255) / 256, 256, 0, stream>>>(dvec, x_edge, eidx,
                                                     W1, b1, W2, b2, node_acc, E);
    node_kernel<<<(N + 255) / 256, 256, 0, stream>>>(node_acc, batch, repsum, gStart, N);
    final_kernel<<<1, 128, 0, stream>>>(repsum, gStart, (float*)d_out, N);
}

// Round 5
// 399.862 us; speedup vs baseline: 2.4762x; 1.3986x over previous
//
#include <hip/hip_runtime.h>

// Problem constants: E=800000 (=3125*256), N=50000, G=16, EMB=64.
#define EMB  64
#define NREP 256   // replica lines for per-graph global atomic spreading

typedef __attribute__((ext_vector_type(8))) short bf16x8;
typedef __attribute__((ext_vector_type(4))) float f32x4;
union BF8 { bf16x8 v; short s[8]; };

// float -> bf16 bits, round-to-nearest-even (finite inputs).
static __device__ __forceinline__ short f2bf(float f) {
    unsigned u = __float_as_uint(f);
    u += 0x7fffu + ((u >> 16) & 1u);
    return (short)(u >> 16);
}

// ---------------------------------------------------------------------------
// Prep: ecnt histogram (scattered int atomics over 50k lines -- the
// measured-OK pattern; R2's 576us was the SAME-LINE gN storm, avoided here)
// + sorted-batch segment starts (zero atomics).
// ---------------------------------------------------------------------------
__global__ __launch_bounds__(256) void prep_kernel(
    const int* __restrict__ eidx, int* __restrict__ ecnt, int E,
    const int* __restrict__ batch, int* __restrict__ gStart, int N)
{
    int t = blockIdx.x * 256 + threadIdx.x;
    if (t < N) {
        int g = batch[t];
        if (t == 0 || batch[t - 1] != g) gStart[g] = t;
    }
    if (t < E) atomicAdd(&ecnt[eidx[t]], 1);
}

// ---------------------------------------------------------------------------
// Edge kernel, transposed-MFMA form. Per wave: 64 edges.
//   A = W1^T in A-layout (A[m=o=mt*16+col][k=i=kt*32+quad*8+j]) -- 32 VGPRs,
//       built once per wave from global (W1 is 16KB, L2-hot).
//   B = X^T  in B-layout (B[k][n=edge=col]) -- lane loads 8 contiguous floats
//       of ITS edge's x row per kt -> two f32x4 loads, x read exactly once.
//   D[m=o][n=edge]: lane holds y at o = mt*16+quad*4+reg for edge col.
// Silu runs DIRECTLY on D registers (no Y LDS, no barrier -- R4's 64KB Y
// tile capped occupancy at 19% and serialized phases). Partial accs
// butterfly-reduced across quads (shfl_xor 16/32). Edge contribution
// scaled by 1/ecnt[n] and dropped into per-graph LDS bins; one 96-wide
// replica-spread global atomic flush per block. node_acc stage (179MB of
// device-atomic write-through + the ~220us node_kernel tail) is GONE.
// ---------------------------------------------------------------------------
__global__ __launch_bounds__(256, 4) void edge_kernel(
    const float* __restrict__ dvec, const float* __restrict__ x_edge,
    const int*   __restrict__ eidx, const int* __restrict__ batch,
    const int*   __restrict__ ecnt,
    const float* __restrict__ W1, const float* __restrict__ b1,
    const float* __restrict__ W2, const float* __restrict__ b2,
    float* __restrict__ repsum, int E)
{
    __shared__ float bins[96];
    __shared__ float sb1[64], sw2[64];
    const int tid = threadIdx.x;
    if (tid < 96) bins[tid] = 0.f;
    if (tid < 64) { sb1[tid] = b1[tid]; sw2[tid] = W2[tid]; }
    __syncthreads();

    const int lane = tid & 63, wave = tid >> 6;
    const int col  = lane & 15, quad = lane >> 4;

    // A fragments: A[m=mt*16+col][k=kt*32+quad*8+j] = W1[k][m]  (bf16 RNE)
    BF8 Af[4][2];
    #pragma unroll
    for (int mt = 0; mt < 4; ++mt)
        #pragma unroll
        for (int kt = 0; kt < 2; ++kt) {
            const float* wp = W1 + (kt * 32 + quad * 8) * 64 + mt * 16 + col;
            #pragma unroll
            for (int j = 0; j < 8; ++j) Af[mt][kt].s[j] = f2bf(wp[j * 64]);
        }

    const float NL2E = -1.442695040888963f;  // -log2(e)
    const float bb2  = b2[0];
    const long  ebase = (long)blockIdx.x * 256 + wave * 64;

    #pragma unroll 1
    for (int nt = 0; nt < 4; ++nt) {
        long e = ebase + nt * 16 + col;          // this lane's edge
        bool valid = (e < E);
        if (!valid) e = 0;

        // Scatter metadata (only quads 0/1 use it) -- issue loads early.
        int   n = 0; float scale = 0.f; int g = 0;
        if (quad < 2) {
            n = eidx[e];
            scale = 1.0f / (float)max(ecnt[n], 1);
            g = batch[n];
        }

        // B fragments: B[k][n=col] = x[e][k]
        const float* xp = x_edge + (size_t)e * EMB + quad * 8;
        f32x4 xa = *(const f32x4*)(xp);
        f32x4 xb = *(const f32x4*)(xp + 4);
        f32x4 xc = *(const f32x4*)(xp + 32);
        f32x4 xd = *(const f32x4*)(xp + 36);
        BF8 B0, B1;
        B0.s[0] = f2bf(xa.x); B0.s[1] = f2bf(xa.y); B0.s[2] = f2bf(xa.z); B0.s[3] = f2bf(xa.w);
        B0.s[4] = f2bf(xb.x); B0.s[5] = f2bf(xb.y); B0.s[6] = f2bf(xb.z); B0.s[7] = f2bf(xb.w);
        B1.s[0] = f2bf(xc.x); B1.s[1] = f2bf(xc.y); B1.s[2] = f2bf(xc.z); B1.s[3] = f2bf(xc.w);
        B1.s[4] = f2bf(xd.x); B1.s[5] = f2bf(xd.y); B1.s[6] = f2bf(xd.z); B1.s[7] = f2bf(xd.w);

        float d0 = dvec[3 * e + 0];
        float d1 = dvec[3 * e + 1];
        float d2 = dvec[3 * e + 2];
        float a[6] = { d0 * d0, d1 * d1, d2 * d2, d0 * d1, d0 * d2, d1 * d2 };

        float acc[6] = { 0.f, 0.f, 0.f, 0.f, 0.f, 0.f };

        #pragma unroll
        for (int mt = 0; mt < 4; ++mt) {
            f32x4 D = { 0.f, 0.f, 0.f, 0.f };
            D = __builtin_amdgcn_mfma_f32_16x16x32_bf16(Af[mt][0].v, B0.v, D, 0, 0, 0);
            D = __builtin_amdgcn_mfma_f32_16x16x32_bf16(Af[mt][1].v, B1.v, D, 0, 0, 0);
            #pragma unroll
            for (int r = 0; r < 4; ++r) {
                int   o  = mt * 16 + quad * 4 + r;
                float y  = D[r];
                float b  = sb1[o];   // quad-broadcast LDS read
                float w2 = sw2[o];
                #pragma unroll
                for (int c = 0; c < 6; ++c) {
                    float z  = fmaf(a[c], y, b);
                    float ex = __builtin_amdgcn_exp2f(z * NL2E);
                    float rr = __builtin_amdgcn_rcpf(1.0f + ex);
                    acc[c]   = fmaf(w2, z * rr, acc[c]);
                }
            }
        }

        // Reduce partials across quads: all lanes end with the full edge sum.
        #pragma unroll
        for (int c = 0; c < 6; ++c) {
            acc[c] += __shfl_xor(acc[c], 16, 64);
            acc[c] += __shfl_xor(acc[c], 32, 64);
        }

        // Scatter: quad0 -> comps 0..2, quad1 -> comps 3..5 (LDS bins).
        if (valid && quad < 2) {
            #pragma unroll
            for (int j = 0; j < 3; ++j) {
                int c = quad * 3 + j;
                atomicAdd(&bins[g * 6 + c], (acc[c] + bb2) * scale);
            }
        }
    }

    __syncthreads();
    if (tid < 96) {
        int rep = blockIdx.x & (NREP - 1);
        atomicAdd(repsum + (size_t)rep * 96 + tid, bins[tid]);
    }
}

// ---------------------------------------------------------------------------
// Final: sum replicas (4-way parallel over reps), node counts from sorted
// boundaries, divide, expand 6 symmetric comps -> 9.
// ---------------------------------------------------------------------------
__global__ __launch_bounds__(384) void final_kernel(
    const float* __restrict__ repsum, const int* __restrict__ gStart,
    float* __restrict__ out, int N)
{
    __shared__ float part[4][96];
    __shared__ float sh[96];
    __shared__ int gs[17];
    int t = threadIdx.x;            // 384 threads
    int r0 = t / 96, gc = t % 96;   // r0 in 0..3
    float s = 0.f;
    #pragma unroll 8
    for (int r = r0; r < NREP; r += 4) s += repsum[(size_t)r * 96 + gc];
    part[r0][gc] = s;
    if (t == 0) {
        gs[16] = N;
        for (int g = 15; g >= 0; --g) {
            unsigned v = (unsigned)gStart[g];
            gs[g] = (v > (unsigned)gs[g + 1]) ? gs[g + 1] : (int)v;  // empty graphs
        }
    }
    __syncthreads();
    if (t < 96) sh[t] = part[0][t] + part[1][t] + part[2][t] + part[3][t];
    __syncthreads();
    if (t < 16) {
        int gN = gs[t + 1] - gs[t];
        float inv = 1.0f / fmaxf((float)gN, 1.0f);
        float m0 = sh[t * 6 + 0] * inv;
        float m1 = sh[t * 6 + 1] * inv;
        float m2 = sh[t * 6 + 2] * inv;
        float m3 = sh[t * 6 + 3] * inv;
        float m4 = sh[t * 6 + 4] * inv;
        float m5 = sh[t * 6 + 5] * inv;
        float* p = out + t * 9;
        p[0] = m0; p[1] = m3; p[2] = m4;
        p[3] = m3; p[4] = m1; p[5] = m5;
        p[6] = m4; p[7] = m5; p[8] = m2;
    }
}

// ---------------------------------------------------------------------------
extern "C" void kernel_launch(void* const* d_in, const int* in_sizes, int n_in,
                              void* d_out, int out_size, void* d_ws, size_t ws_size,
                              hipStream_t stream) {
    const float* dvec   = (const float*)d_in[0];   // [E,3]
    const float* x_edge = (const float*)d_in[1];   // [E,64]
    const int*   eidx   = (const int*)d_in[2];     // [E]
    const int*   batch  = (const int*)d_in[3];     // [N] sorted
    const float* W1     = (const float*)d_in[6];   // [64,64] (in,out)
    const float* b1     = (const float*)d_in[7];   // [64]
    const float* W2     = (const float*)d_in[8];   // [64,1]
    const float* b2     = (const float*)d_in[9];   // [1]

    int E = in_sizes[0] / 3;   // 800000
    int N = in_sizes[3];       // 50000

    // ws: ecnt[N] int | repsum[NREP*96] float | gStart[17] int  (contiguous)
    int*   ecnt   = (int*)d_ws;
    float* repsum = (float*)(ecnt + N);
    int*   gStart = (int*)(repsum + (size_t)NREP * 96);

    hipMemsetAsync(d_ws, 0, ((size_t)N + (size_t)NREP * 96) * 4, stream);
    hipMemsetAsync(gStart, 0xFF, 17 * 4, stream);

    int blocks = (E + 255) / 256;   // covers both E and N in prep
    prep_kernel<<<blocks, 256, 0, stream>>>(eidx, ecnt, E, batch, gStart, N);
    edge_kernel<<<blocks, 256, 0, stream>>>(dvec, x_edge, eidx, batch, ecnt,
                                            W1, b1, W2, b2, repsum, E);
    final_kernel<<<1, 384, 0, stream>>>(repsum, gStart, (float*)d_out, N);
}